// Round 2
// 529.096 us; speedup vs baseline: 1.0097x; 1.0097x over previous
//
#include <hip/hip_runtime.h>

// PrototypeBank steady-state update, MI355X/gfx950.  Round 6.
//   emb:    [131072, 512] fp32   protos: [1024, 512] fp32
//   out[k]: count>0 ? normalize(0.9*p + 0.1*mean(norm_emb assigned to k)) : p
//
// Round-6: Round-5's full 64-iter unroll may have blown compile time /
// regalloc (container failed twice with no diagnostics).  Same theory
// (assign is latency-bound: MFMA 27% / LDS 27% / VALU 29%, VGPR 52/128),
// bounded unroll 8 instead: 8-iteration SSA window hoists pbf L2 loads
// ~4 deep while staying well under the 128-VGPR cap.
//   - norm_protos zeroes psum (removes serialized hipMemsetAsync launch).

#define D 512
#define NPROTO 1024
#define ROWS 64          // embedding rows per workgroup in k1

typedef __attribute__((ext_vector_type(8)))  unsigned short ushort8;
typedef __attribute__((ext_vector_type(8)))  __bf16 bfrag8;
typedef __attribute__((ext_vector_type(16))) float f32x16;

static __device__ inline unsigned short f2bf(float f) {
    unsigned int u = __float_as_uint(f);
    u = u + 0x7FFFu + ((u >> 16) & 1u);   // round-to-nearest-even
    return (unsigned short)(u >> 16);
}

// ---------------- k0: normalize prototypes -> packed bf16 A-fragments ----------------
// Packed for 32x32x16 A-operand: group g32 = p>>5 (32 protos), k-step ks (16 cols).
// Consumer lane l reads ((g32*32+ks)*64 + l)*8 shorts: lane l -> proto g32*32+(l&31),
// k = ks*16 + (l>>5)*8.  Same k-order convention used for B, so any k permutation
// is consistent across operands.  Also zeroes psum (1024x512 fp32) and counts.
__global__ __launch_bounds__(256) void norm_protos_kernel(
    const float* __restrict__ protos, unsigned short* __restrict__ pbf,
    int* __restrict__ counts, float* __restrict__ psum)
{
    const int wave = threadIdx.x >> 6, lane = threadIdx.x & 63;
    const int row = blockIdx.x * 4 + wave;            // grid 256 -> 1024 rows
    const float* src = protos + (size_t)row * D + lane * 8;
    float4 v0 = *(const float4*)src;
    float4 v1 = *(const float4*)(src + 4);
    float ss = v0.x*v0.x + v0.y*v0.y + v0.z*v0.z + v0.w*v0.w
             + v1.x*v1.x + v1.y*v1.y + v1.z*v1.z + v1.w*v1.w;
    #pragma unroll
    for (int off = 32; off > 0; off >>= 1) ss += __shfl_xor(ss, off, 64);
    const float inv = 1.0f / fmaxf(sqrtf(ss), 1e-6f);
    ushort8 w;
    w[0] = f2bf(v0.x*inv); w[1] = f2bf(v0.y*inv); w[2] = f2bf(v0.z*inv); w[3] = f2bf(v0.w*inv);
    w[4] = f2bf(v1.x*inv); w[5] = f2bf(v1.y*inv); w[6] = f2bf(v1.z*inv); w[7] = f2bf(v1.w*inv);
    // lane holds k-chunk c = lane (8 bf16): ks = c>>1, half = c&1
    const size_t dst = (size_t)(row >> 5) * 16384 + (lane >> 1) * 512
                     + (lane & 1) * 256 + (row & 31) * 8;
    *(ushort8*)(pbf + dst) = w;
    // zero psum: 524288 floats over 65536 threads -> 2 float4 each
    const int gid = blockIdx.x * 256 + threadIdx.x;
    const float4 z = make_float4(0.f, 0.f, 0.f, 0.f);
    ((float4*)psum)[gid * 2]     = z;
    ((float4*)psum)[gid * 2 + 1] = z;
    if (blockIdx.x == 0) ((int4*)counts)[threadIdx.x] = (int4){0, 0, 0, 0};
}

// ---------------- k1: argmax over 1024 protos (32x32x16 bf16 MFMA) ----------------
// LDS B-tile: 64 emb rows x 512 bf16, 16B-chunk XOR swizzle slot = c ^ (row&7).
// 8 waves; wave = 64 protos x 64 emb cols; 2 ng passes cover 1024 protos.
__global__ __launch_bounds__(512, 4) void assign_kernel(
    const float* __restrict__ emb, const unsigned short* __restrict__ pbf,
    int* __restrict__ assign, float* __restrict__ invnorm, int* __restrict__ counts)
{
    __shared__ __align__(16) unsigned short eT[ROWS * D];   // 64 KB
    __shared__ float swmax[8][64];                           // 2 KB
    __shared__ int   swidx[8][64];                           // 2 KB
    const int tid = threadIdx.x;
    const int wave = tid >> 6, lane = tid & 63;
    const int rowbase = blockIdx.x * ROWS;
    const int c32 = lane & 31, h = lane >> 5;

    // --- stage: 8 rows/wave, RAW bf16 (||e|| doesn't change argmax); invnorm saved.
    for (int rr = 0; rr < 8; ++rr) {
        const int rloc = wave * 8 + rr;
        const float* src = emb + (size_t)(rowbase + rloc) * D + lane * 8;
        float4 v0 = *(const float4*)src;
        float4 v1 = *(const float4*)(src + 4);
        float ss = v0.x*v0.x + v0.y*v0.y + v0.z*v0.z + v0.w*v0.w
                 + v1.x*v1.x + v1.y*v1.y + v1.z*v1.z + v1.w*v1.w;
        #pragma unroll
        for (int off = 32; off > 0; off >>= 1) ss += __shfl_xor(ss, off, 64);
        if (lane == 0) invnorm[rowbase + rloc] = 1.0f / fmaxf(sqrtf(ss), 1e-6f);
        ushort8 w;
        w[0] = f2bf(v0.x); w[1] = f2bf(v0.y); w[2] = f2bf(v0.z); w[3] = f2bf(v0.w);
        w[4] = f2bf(v1.x); w[5] = f2bf(v1.y); w[6] = f2bf(v1.z); w[7] = f2bf(v1.w);
        const int slot = lane ^ (rloc & 7);
        *(ushort8*)(&eT[rloc * D + slot * 8]) = w;
    }
    __syncthreads();

    float rv0 = -3.4e38f, rv1 = -3.4e38f;
    int   ri0 = 0,        ri1 = 0;

    // B LDS addresses: row r0=c32 (nt0), r1=32+c32 (nt1); (r0&7)==(r1&7)==(c32&7)
    const int bbase0 = c32 * D;            // shorts
    const int bbase1 = (32 + c32) * D;
    const int rxor = c32 & 7;

    for (int ng = 0; ng < 2; ++ng) {
        const int pbase = ng * 512 + wave * 64;
        const unsigned short* pa0 = pbf + (size_t)(pbase >> 5) * 16384 + lane * 8;
        const unsigned short* pa1 = pa0 + 16384;

        f32x16 acc00 = (f32x16)(0.f), acc01 = (f32x16)(0.f);
        f32x16 acc10 = (f32x16)(0.f), acc11 = (f32x16)(0.f);

        // Bounded 8-iter unroll: SSA window deep enough to hoist the pbf
        // L2 loads (~200 cyc) ~4 iterations ahead, small enough for clean
        // regalloc under the 128-VGPR cap.
        #pragma unroll 8
        for (int ks = 0; ks < 32; ++ks) {
            const bfrag8 a0 = *(const bfrag8*)(pa0 + ks * 512);
            const bfrag8 a1 = *(const bfrag8*)(pa1 + ks * 512);
            const int slot = ((ks * 2 + h) ^ rxor) * 8;
            const bfrag8 b0 = *(const bfrag8*)(&eT[bbase0 + slot]);
            const bfrag8 b1 = *(const bfrag8*)(&eT[bbase1 + slot]);
            acc00 = __builtin_amdgcn_mfma_f32_32x32x16_bf16(a0, b0, acc00, 0, 0, 0);
            acc01 = __builtin_amdgcn_mfma_f32_32x32x16_bf16(a0, b1, acc01, 0, 0, 0);
            acc10 = __builtin_amdgcn_mfma_f32_32x32x16_bf16(a1, b0, acc10, 0, 0, 0);
            acc11 = __builtin_amdgcn_mfma_f32_32x32x16_bf16(a1, b1, acc11, 0, 0, 0);
        }

        // In-register argmax over protos.  C layout (32x32): col=lane&31,
        // row = (reg&3) + 8*(reg>>2) + 4*(lane>>5).  For fixed lane, iterating
        // reg 0..15 then mt 0..1 gives strictly ascending proto index ->
        // strict > keeps the first max (jnp.argmax semantics).
        float bv0 = -3.4e38f, bv1 = -3.4e38f;
        int   bi0 = 0,        bi1 = 0;
        #pragma unroll
        for (int j = 0; j < 16; ++j) {
            const int row = (j & 3) + 8 * (j >> 2) + 4 * h;
            const float v0 = acc00[j], v1 = acc01[j];
            if (v0 > bv0) { bv0 = v0; bi0 = pbase + row; }
            if (v1 > bv1) { bv1 = v1; bi1 = pbase + row; }
        }
        #pragma unroll
        for (int j = 0; j < 16; ++j) {
            const int row = 32 + (j & 3) + 8 * (j >> 2) + 4 * h;
            const float v0 = acc10[j], v1 = acc11[j];
            if (v0 > bv0) { bv0 = v0; bi0 = pbase + row; }
            if (v1 > bv1) { bv1 = v1; bi1 = pbase + row; }
        }
        // half-merge (other half owns interleaved rows; tie-break on index)
        {
            const float ov = __shfl_xor(bv0, 32, 64);
            const int   oi = __shfl_xor(bi0, 32, 64);
            if (ov > bv0 || (ov == bv0 && oi < bi0)) { bv0 = ov; bi0 = oi; }
        }
        {
            const float ov = __shfl_xor(bv1, 32, 64);
            const int   oi = __shfl_xor(bi1, 32, 64);
            if (ov > bv1 || (ov == bv1 && oi < bi1)) { bv1 = ov; bi1 = oi; }
        }
        // ng ascending: strictly-greater replaces; ties keep older (smaller idx)
        if (bv0 > rv0) { rv0 = bv0; ri0 = bi0; }
        if (bv1 > rv1) { rv1 = bv1; ri1 = bi1; }
    }

    if (h == 0) {
        swmax[wave][c32]      = rv0;  swidx[wave][c32]      = ri0;
        swmax[wave][32 + c32] = rv1;  swidx[wave][32 + c32] = ri1;
    }
    __syncthreads();

    if (tid < 64) {
        float v = swmax[0][tid]; int idx = swidx[0][tid];
        #pragma unroll
        for (int w = 1; w < 8; ++w) {
            const float ov = swmax[w][tid];
            const int   oi = swidx[w][tid];
            if (ov > v || (ov == v && oi < idx)) { v = ov; idx = oi; }
        }
        assign[rowbase + tid] = idx;
        atomicAdd(&counts[idx], 1);
    }
}

// ---------------- k2: prefix sum + segment work-item list ----------------
__global__ __launch_bounds__(1024) void prefix_kernel(
    const int* __restrict__ counts, int* __restrict__ offsets,
    int* __restrict__ cursor, int* __restrict__ items, int* __restrict__ nitems)
{
    __shared__ int sc[NPROTO];
    const int t = threadIdx.x;
    const int c = counts[t];
    sc[t] = c;
    __syncthreads();
    #pragma unroll
    for (int off = 1; off < NPROTO; off <<= 1) {
        const int v = (t >= off) ? sc[t - off] : 0;
        __syncthreads();
        sc[t] += v;
        __syncthreads();
    }
    const int excl = sc[t] - c;
    offsets[t] = excl;
    cursor[t]  = excl;

    // second scan: segments of <=256 rows
    const int nseg = (c + 255) >> 8;
    __syncthreads();
    sc[t] = nseg;
    __syncthreads();
    #pragma unroll
    for (int off = 1; off < NPROTO; off <<= 1) {
        const int v = (t >= off) ? sc[t - off] : 0;
        __syncthreads();
        sc[t] += v;
        __syncthreads();
    }
    const int segexcl = sc[t] - nseg;
    for (int s = 0; s < nseg; ++s) items[segexcl + s] = (t << 12) | s;
    if (t == NPROTO - 1) *nitems = sc[NPROTO - 1];
}

// ---------------- k3: scatter row indices into per-proto bins ----------------
__global__ __launch_bounds__(256) void scatter_kernel(
    const int* __restrict__ assign, int* __restrict__ cursor, int* __restrict__ bin)
{
    const int i = blockIdx.x * 256 + threadIdx.x;
    const int k = assign[i];
    const int pos = atomicAdd(&cursor[k], 1);
    bin[pos] = i;
}

// ---------------- k4A: per-segment partial sums -> psum (atomic fp32) ----------------
__global__ __launch_bounds__(256) void psum_kernel(
    const float* __restrict__ emb, const int* __restrict__ bin,
    const int* __restrict__ counts, const int* __restrict__ offsets,
    const float* __restrict__ invnorm, const int* __restrict__ items,
    const int* __restrict__ nitems, float* __restrict__ psum)
{
    if ((int)blockIdx.x >= *nitems) return;
    __shared__ float4 part[128];
    const int item = items[blockIdx.x];
    const int k = item >> 12, seg = item & 4095;
    const int off = offsets[k], cnt = counts[k];
    const int s0 = seg * 256;
    const int s1 = min(s0 + 256, cnt);
    const int t = threadIdx.x;
    const int par = t >> 7, colg = (t & 127) * 4;
    float4 acc = make_float4(0.f, 0.f, 0.f, 0.f);

    int jb = s0;
    for (; jb + 4 <= s1; jb += 4) {
        const int r0 = bin[off + jb + par];
        const int r1 = bin[off + jb + 2 + par];
        const float sc0 = invnorm[r0], sc1 = invnorm[r1];
        const float4 v0 = *(const float4*)(emb + (size_t)r0 * D + colg);
        const float4 v1 = *(const float4*)(emb + (size_t)r1 * D + colg);
        acc.x += v0.x * sc0; acc.y += v0.y * sc0; acc.z += v0.z * sc0; acc.w += v0.w * sc0;
        acc.x += v1.x * sc1; acc.y += v1.y * sc1; acc.z += v1.z * sc1; acc.w += v1.w * sc1;
    }
    if (jb + 2 <= s1) {
        const int r = bin[off + jb + par];
        const float sc = invnorm[r];
        const float4 v = *(const float4*)(emb + (size_t)r * D + colg);
        acc.x += v.x * sc; acc.y += v.y * sc; acc.z += v.z * sc; acc.w += v.w * sc;
        jb += 2;
    }
    if (par == 0 && jb < s1) {
        const int r = bin[off + jb];
        const float sc = invnorm[r];
        const float4 v = *(const float4*)(emb + (size_t)r * D + colg);
        acc.x += v.x * sc; acc.y += v.y * sc; acc.z += v.z * sc; acc.w += v.w * sc;
    }

    if (par == 1) part[t & 127] = acc;
    __syncthreads();
    if (par == 0) {
        const float4 o = part[t];
        float* dst = psum + (size_t)k * D + colg;
        atomicAdd(dst + 0, acc.x + o.x);
        atomicAdd(dst + 1, acc.y + o.y);
        atomicAdd(dst + 2, acc.z + o.z);
        atomicAdd(dst + 3, acc.w + o.w);
    }
}

// ---------------- k4B: EMA + normalize ----------------
__global__ __launch_bounds__(128) void final_kernel(
    const float* __restrict__ protos, const float* __restrict__ psum,
    const int* __restrict__ counts, float* __restrict__ out)
{
    __shared__ float red[2];
    const int k = blockIdx.x, t = threadIdx.x;
    const int colg = t * 4;
    const int cnt = counts[k];
    const float denom = fmaxf((float)cnt, 1.0f);
    const float4 s  = *(const float4*)(psum + (size_t)k * D + colg);
    const float4 p4 = *(const float4*)(protos + (size_t)k * D + colg);
    float4 u;
    u.x = 0.9f * p4.x + 0.1f * s.x / denom;
    u.y = 0.9f * p4.y + 0.1f * s.y / denom;
    u.z = 0.9f * p4.z + 0.1f * s.z / denom;
    u.w = 0.9f * p4.w + 0.1f * s.w / denom;
    float ss = u.x*u.x + u.y*u.y + u.z*u.z + u.w*u.w;
    #pragma unroll
    for (int off = 32; off > 0; off >>= 1) ss += __shfl_xor(ss, off, 64);
    if ((t & 63) == 0) red[t >> 6] = ss;
    __syncthreads();
    const float tot = red[0] + red[1];
    const float inv = 1.0f / fmaxf(sqrtf(tot), 1e-6f);
    float4 o;
    o.x = (cnt > 0) ? u.x * inv : p4.x;
    o.y = (cnt > 0) ? u.y * inv : p4.y;
    o.z = (cnt > 0) ? u.z * inv : p4.z;
    o.w = (cnt > 0) ? u.w * inv : p4.w;
    *(float4*)(out + (size_t)k * D + colg) = o;
}

extern "C" void kernel_launch(void* const* d_in, const int* in_sizes, int n_in,
                              void* d_out, int out_size, void* d_ws, size_t ws_size,
                              hipStream_t stream)
{
    const float* emb    = (const float*)d_in[0];
    const float* protos = (const float*)d_in[1];
    float* out = (float*)d_out;
    const int n_emb = in_sizes[0] / D;        // 131072

    char* ws = (char*)d_ws;
    unsigned short* pbf = (unsigned short*)ws;                 // 1 MB packed bf16 protos
    int*   assign  = (int*)  (ws + (1 << 20));                 // 512 KB
    float* invnorm = (float*)(ws + (1 << 20) + (512 << 10));   // 512 KB
    int*   counts  = (int*)  (ws + (2 << 20));                 // 4 KB
    int*   offsets = (int*)  (ws + (2 << 20) + (4 << 10));     // 4 KB
    int*   cursor  = (int*)  (ws + (2 << 20) + (8 << 10));     // 4 KB
    int*   nitems  = (int*)  (ws + (2 << 20) + (12 << 10));    // 4 KB
    int*   items   = (int*)  (ws + (2 << 20) + (16 << 10));    // 8 KB (<=1536)
    int*   bin     = (int*)  (ws + (2 << 20) + (24 << 10));    // 512 KB
    float* psum    = (float*)(ws + (2 << 20) + (24 << 10) + (512 << 10)); // 2 MB

    norm_protos_kernel<<<NPROTO / 4, 256, 0, stream>>>(protos, pbf, counts, psum);
    assign_kernel<<<n_emb / ROWS, 512, 0, stream>>>(emb, pbf, assign, invnorm, counts);
    prefix_kernel<<<1, 1024, 0, stream>>>(counts, offsets, cursor, items, nitems);
    scatter_kernel<<<n_emb / 256, 256, 0, stream>>>(assign, cursor, bin);
    psum_kernel<<<1536, 256, 0, stream>>>(emb, bin, counts, offsets, invnorm,
                                          items, nitems, psum);
    final_kernel<<<NPROTO, 128, 0, stream>>>(protos, psum, counts, out);
}